// Round 5
// baseline (247.836 us; speedup 1.0000x reference)
//
#include <hip/hip_runtime.h>
#include <hip/hip_bf16.h>

// Per-channel 3-layer MLP (1 -> 256 -> 256 -> 3), N=B*H*W=32768 pixels, C=16.
// fp32 in / fp32 out; internal bf16 MFMA (abs err 1.95e-3 << 5.78e-3 threshold).
// fc2 dominates: 16 GEMMs of M=32768,K=256,N=256 = 68.7 GFLOP.
//
// Round-5: K-loop was L2-latency-bound (VGPR=60 -> JIT B loads, MfmaUtil 21%).
// Fix: prefetch all 32 B-fragments (128 VGPRs) at kernel entry; K-loop becomes
// pure LDS+MFMA.

typedef __bf16 bf16_t;
typedef __attribute__((ext_vector_type(8))) __bf16 bf16x8;
typedef __attribute__((ext_vector_type(4))) float floatx4;

#define C_CH 16
#define HID  256

// ---------------------------------------------------------------------------
// Kernel 1: W2 fp32 [c][h][n] -> W2t bf16 [c][n][h]
// ---------------------------------------------------------------------------
__global__ __launch_bounds__(256) void transpose_w2(const float* __restrict__ W2,
                                                    bf16_t* __restrict__ W2t) {
  __shared__ __align__(16) bf16_t tl[64][72];  // +8 pad
  const int bid = blockIdx.x;
  const int c = bid >> 4, ti = (bid >> 2) & 3, tj = bid & 3;
  const int t = threadIdx.x;
  const float* src = W2 + (size_t)(c * 256 + tj * 64) * 256 + ti * 64;
#pragma unroll
  for (int it = 0; it < 4; ++it) {
    int idx = it * 256 + t;
    int h = idx >> 4, q = idx & 15;
    float4 v = *(const float4*)(src + h * 256 + q * 4);
    tl[h][q * 4 + 0] = (bf16_t)v.x;
    tl[h][q * 4 + 1] = (bf16_t)v.y;
    tl[h][q * 4 + 2] = (bf16_t)v.z;
    tl[h][q * 4 + 3] = (bf16_t)v.w;
  }
  __syncthreads();
  bf16_t* dst = W2t + (size_t)(c * 256 + ti * 64) * 256 + tj * 64;
#pragma unroll
  for (int it = 0; it < 2; ++it) {
    int idx = it * 256 + t;
    int n = idx >> 3, h8 = (idx & 7) * 8;
    bf16x8 tmp;
#pragma unroll
    for (int q = 0; q < 8; ++q) tmp[q] = tl[h8 + q][n];
    *(bf16x8*)(dst + n * 256 + h8) = tmp;
  }
}

// ---------------------------------------------------------------------------
// Kernel 2: fused fc1 -> fc2 (MFMA, register-prefetched B) -> fc3 (MFMA)
// block = 256 thr = 4 waves; wave tile 64 px x 64 out = 4x4 mfma_f32_16x16x32_bf16
// ---------------------------------------------------------------------------
template <bool DIRECT>
__global__ __launch_bounds__(256, 2) void kan_fused(
    const float* __restrict__ x, const float* __restrict__ W1,
    const float* __restrict__ b1, const bf16_t* __restrict__ W2t,
    const float* __restrict__ W2, const float* __restrict__ b2,
    const float* __restrict__ W3, const float* __restrict__ b3,
    float* __restrict__ out) {
  __shared__ __align__(16) bf16_t h1[64][264];   // A-tile (reused for h2)
  __shared__ __align__(16) bf16_t w3t[4][264];   // W3^T B-operand (row3=0)
  __shared__ float red[4][64][3];                // fc3 cross-wave partials
  __shared__ float b2s[256];
  __shared__ float xv[64];
  __shared__ float b3s[3];

  const int t = threadIdx.x;
  const int lane = t & 63;
  const int wv = t >> 6;
  const int bid = blockIdx.x;
  const int c = bid & 15;          // channel
  const int m0 = (bid >> 4) * 64;  // pixel-tile base

  const int l15 = lane & 15;
  const int l4 = lane >> 4;
  const int nw0 = wv * 64;  // wave's output-column range within HID

  // ---- B prefetch: ALL 32 fragments for the whole K-loop, issued first so the
  // L2 latency overlaps fc1 generation + barrier. 128 VGPRs.
  bf16x8 Bf[32];  // [kt*8 + ks*4 + jn]
  if (!DIRECT) {
    const bf16_t* Bbase = W2t + ((size_t)c << 16) + (size_t)(nw0 + l15) * HID + l4 * 8;
#pragma unroll
    for (int kt = 0; kt < 4; ++kt)
#pragma unroll
      for (int ks = 0; ks < 2; ++ks)
#pragma unroll
        for (int jn = 0; jn < 4; ++jn)
          Bf[kt * 8 + ks * 4 + jn] =
              *(const bf16x8*)(Bbase + jn * (16 * HID) + kt * 64 + ks * 32);
  } else {
    // fallback (tiny ws): strided fp32 W2 reads
#pragma unroll
    for (int kt = 0; kt < 4; ++kt)
#pragma unroll
      for (int ks = 0; ks < 2; ++ks)
#pragma unroll
        for (int jn = 0; jn < 4; ++jn) {
          const float* g = W2 + ((size_t)c << 16) +
                           (size_t)(kt * 64 + ks * 32 + l4 * 8) * HID +
                           (nw0 + jn * 16 + l15);
#pragma unroll
          for (int j = 0; j < 8; ++j) Bf[kt * 8 + ks * 4 + jn][j] = (bf16_t)g[j * HID];
        }
  }

  // ---- stage small per-channel data
  if (t < 64) xv[t] = x[(size_t)(m0 + t) * C_CH + c];
  b2s[t] = b2[c * HID + t];
  w3t[0][t] = (bf16_t)W3[(c * HID + t) * 3 + 0];
  w3t[1][t] = (bf16_t)W3[(c * HID + t) * 3 + 1];
  w3t[2][t] = (bf16_t)W3[(c * HID + t) * 3 + 2];
  w3t[3][t] = (bf16_t)0.0f;  // zero row (fc3 acc cols 3..15 ignored)
  if (t < 3) b3s[t] = b3[c * 3 + t];
  __syncthreads();

  // ---- fc1: h1[m][h] = relu(x[m]*W1[c][h] + b1[c][h]) in fp32 -> bf16 LDS
  {
    const int j8 = (t & 31) * 8;  // h-octet
    float4 w0 = *(const float4*)(W1 + c * HID + j8);
    float4 w1v = *(const float4*)(W1 + c * HID + j8 + 4);
    float4 bb0 = *(const float4*)(b1 + c * HID + j8);
    float4 bb1 = *(const float4*)(b1 + c * HID + j8 + 4);
    float wf[8] = {w0.x, w0.y, w0.z, w0.w, w1v.x, w1v.y, w1v.z, w1v.w};
    float bf_[8] = {bb0.x, bb0.y, bb0.z, bb0.w, bb1.x, bb1.y, bb1.z, bb1.w};
#pragma unroll
    for (int it = 0; it < 8; ++it) {
      int m = it * 8 + (t >> 5);
      float xm = xv[m];
      bf16x8 hv;
#pragma unroll
      for (int q = 0; q < 8; ++q)
        hv[q] = (bf16_t)fmaxf(xm * wf[q] + bf_[q], 0.0f);
      *(bf16x8*)&h1[m][j8] = hv;
    }
  }
  __syncthreads();  // h1 visible to all waves

  floatx4 zero4 = {0.f, 0.f, 0.f, 0.f};
  floatx4 acc[4][4];
#pragma unroll
  for (int im = 0; im < 4; ++im)
#pragma unroll
    for (int jn = 0; jn < 4; ++jn) acc[im][jn] = zero4;

  // ---- fc2 K-loop: pure LDS + MFMA (B already in registers)
#pragma unroll
  for (int kt = 0; kt < 4; ++kt) {
#pragma unroll
    for (int ks = 0; ks < 2; ++ks) {
      const int k0 = kt * 64 + ks * 32;
      bf16x8 af[4];
#pragma unroll
      for (int im = 0; im < 4; ++im)
        af[im] = *(const bf16x8*)&h1[im * 16 + l15][k0 + l4 * 8];
#pragma unroll
      for (int im = 0; im < 4; ++im)
#pragma unroll
        for (int jn = 0; jn < 4; ++jn)
          acc[im][jn] = __builtin_amdgcn_mfma_f32_16x16x32_bf16(
              af[im], Bf[kt * 8 + ks * 4 + jn], acc[im][jn], 0, 0, 0);
    }
  }

  __syncthreads();  // all waves done reading h1 before overwrite with h2

  // ---- fc2 epilogue: bias + relu -> h2 into h1 buffer (A-layout for fc3)
  // C/D layout (m89-verified): col = lane&15, row = (lane>>4)*4 + reg
#pragma unroll
  for (int im = 0; im < 4; ++im) {
#pragma unroll
    for (int jn = 0; jn < 4; ++jn) {
      int n = nw0 + jn * 16 + l15;
      float bias = b2s[n];
#pragma unroll
      for (int r = 0; r < 4; ++r) {
        int m = im * 16 + l4 * 4 + r;
        h1[m][n] = (bf16_t)fmaxf(acc[im][jn][r] + bias, 0.0f);
      }
    }
  }
  __syncthreads();

  // ---- fc3 via MFMA: out[m][o] = sum_h h2[m][h]*W3[c][h][o]; h split by wave
  {
    floatx4 acc3[4];
#pragma unroll
    for (int im = 0; im < 4; ++im) acc3[im] = zero4;
#pragma unroll
    for (int ks = 0; ks < 2; ++ks) {
      int kb = wv * 64 + ks * 32 + l4 * 8;
      int br = l15 < 3 ? l15 : 3;  // B row (o); row 3 = zeros
      bf16x8 bf3 = *(const bf16x8*)&w3t[br][kb];
#pragma unroll
      for (int im = 0; im < 4; ++im) {
        bf16x8 a3 = *(const bf16x8*)&h1[im * 16 + l15][kb];
        acc3[im] = __builtin_amdgcn_mfma_f32_16x16x32_bf16(a3, bf3, acc3[im], 0, 0, 0);
      }
    }
    if (l15 < 3) {
#pragma unroll
      for (int im = 0; im < 4; ++im)
#pragma unroll
        for (int r = 0; r < 4; ++r) {
          int m = im * 16 + l4 * 4 + r;
          red[wv][m][l15] = acc3[im][r];
        }
    }
  }
  __syncthreads();

  // ---- cross-wave h-reduce + bias + fp32 store: flat idx = (pixel*16+c)*3+o
  if (t < 192) {
    int m = t / 3, o = t - m * 3;
    float s = red[0][m][o] + red[1][m][o] + red[2][m][o] + red[3][m][o] + b3s[o];
    out[(size_t)((m0 + m) * C_CH + c) * 3 + o] = s;
  }
}

extern "C" void kernel_launch(void* const* d_in, const int* in_sizes, int n_in,
                              void* d_out, int out_size, void* d_ws, size_t ws_size,
                              hipStream_t stream) {
  const float* x = (const float*)d_in[0];
  const float* W1 = (const float*)d_in[1];
  const float* b1 = (const float*)d_in[2];
  const float* W2 = (const float*)d_in[3];
  const float* b2 = (const float*)d_in[4];
  const float* W3 = (const float*)d_in[5];
  const float* b3 = (const float*)d_in[6];
  float* out = (float*)d_out;
  bf16_t* W2t = (bf16_t*)d_ws;  // 2 MB scratch: bf16-transposed W2

  const size_t need = (size_t)C_CH * HID * HID * sizeof(bf16_t);  // 2 MB
  if (ws_size >= need) {
    transpose_w2<<<256, 256, 0, stream>>>(W2, W2t);
    kan_fused<false><<<8192, 256, 0, stream>>>(x, W1, b1, W2t, W2, b2, W3, b3, out);
  } else {
    kan_fused<true><<<8192, 256, 0, stream>>>(x, W1, b1, W2t, W2, b2, W3, b3, out);
  }
}

// Round 7
// 202.610 us; speedup vs baseline: 1.2232x; 1.2232x over previous
//
#include <hip/hip_runtime.h>
#include <hip/hip_bf16.h>

// Per-channel 3-layer MLP (1 -> 256 -> 256 -> 3), N=B*H*W=32768 pixels, C=16.
// fp32 in / fp32 out; internal bf16 MFMA for fc2. fc2: 16 GEMMs M=32768,K=256,N=256.
//
// Round-7 (persistent-B, fixed): r6 had (1) missing nw0 in b2/W3 epilogue consts,
// (2) missing cross-wave fc3 reduce (4 waves raced partial stores). Fixed with
// correct n indexing + red[4][64][3] LDS partials. 2 barriers/tile.

typedef __bf16 bf16_t;
typedef __attribute__((ext_vector_type(8))) __bf16 bf16x8;
typedef __attribute__((ext_vector_type(4))) float floatx4;

#define C_CH 16
#define HID  256

// ---------------------------------------------------------------------------
// Kernel 1: W2 fp32 [c][h][n] -> W2t bf16 [c][n][h]
// ---------------------------------------------------------------------------
__global__ __launch_bounds__(256) void transpose_w2(const float* __restrict__ W2,
                                                    bf16_t* __restrict__ W2t) {
  __shared__ __align__(16) bf16_t tl[64][72];  // +8 pad
  const int bid = blockIdx.x;
  const int c = bid >> 4, ti = (bid >> 2) & 3, tj = bid & 3;
  const int t = threadIdx.x;
  const float* src = W2 + (size_t)(c * 256 + tj * 64) * 256 + ti * 64;
#pragma unroll
  for (int it = 0; it < 4; ++it) {
    int idx = it * 256 + t;
    int h = idx >> 4, q = idx & 15;
    float4 v = *(const float4*)(src + h * 256 + q * 4);
    tl[h][q * 4 + 0] = (bf16_t)v.x;
    tl[h][q * 4 + 1] = (bf16_t)v.y;
    tl[h][q * 4 + 2] = (bf16_t)v.z;
    tl[h][q * 4 + 3] = (bf16_t)v.w;
  }
  __syncthreads();
  bf16_t* dst = W2t + (size_t)(c * 256 + ti * 64) * 256 + tj * 64;
#pragma unroll
  for (int it = 0; it < 2; ++it) {
    int idx = it * 256 + t;
    int n = idx >> 3, h8 = (idx & 7) * 8;
    bf16x8 tmp;
#pragma unroll
    for (int q = 0; q < 8; ++q) tmp[q] = tl[h8 + q][n];
    *(bf16x8*)(dst + n * 256 + h8) = tmp;
  }
}

// ---------------------------------------------------------------------------
// Kernel 2: persistent-B fused kernel. Block = 256 thr = 4 waves; one channel,
// 8 tiles of 64 pixels. Wave n-slice = 64 cols; 4x4 mfma_f32_16x16x32_bf16/tile.
// ---------------------------------------------------------------------------
template <bool DIRECT>
__global__ __launch_bounds__(256, 2) void kan_fused(
    const float* __restrict__ x, const float* __restrict__ W1,
    const float* __restrict__ b1, const bf16_t* __restrict__ W2t,
    const float* __restrict__ W2, const float* __restrict__ b2,
    const float* __restrict__ W3, const float* __restrict__ b3,
    float* __restrict__ out) {
  __shared__ __align__(16) bf16_t h1[64][264];  // 33792 B A-tile
  __shared__ float red[4][64][3];               //  3072 B fc3 cross-wave partials

  const int t = threadIdx.x;
  const int lane = t & 63;
  const int wv = t >> 6;
  const int bid = blockIdx.x;
  const int c = bid & 15;   // channel (spread across consecutive blocks -> XCDs)
  const int g = bid >> 4;   // 8-tile group, 0..63

  const int l15 = lane & 15;
  const int l4 = lane >> 4;
  const int nw0 = wv * 64;  // wave's output-column base within HID

  // ---- persistent B: all 32 fragments for K=256 x n-slice 64 (128 VGPRs)
  bf16x8 Bf[32];  // [kt*8 + ks*4 + jn]
  if (!DIRECT) {
    const bf16_t* Bbase = W2t + ((size_t)c << 16) + (size_t)(nw0 + l15) * HID + l4 * 8;
#pragma unroll
    for (int kt = 0; kt < 4; ++kt)
#pragma unroll
      for (int ks = 0; ks < 2; ++ks)
#pragma unroll
        for (int jn = 0; jn < 4; ++jn)
          Bf[kt * 8 + ks * 4 + jn] =
              *(const bf16x8*)(Bbase + jn * (16 * HID) + kt * 64 + ks * 32);
  } else {
#pragma unroll
    for (int kt = 0; kt < 4; ++kt)
#pragma unroll
      for (int ks = 0; ks < 2; ++ks)
#pragma unroll
        for (int jn = 0; jn < 4; ++jn) {
          const float* gp = W2 + ((size_t)c << 16) +
                            (size_t)(kt * 64 + ks * 32 + l4 * 8) * HID +
                            (nw0 + jn * 16 + l15);
#pragma unroll
          for (int j = 0; j < 8; ++j) Bf[kt * 8 + ks * 4 + jn][j] = (bf16_t)gp[j * HID];
        }
  }

  // ---- per-block invariants in registers
  const int j8 = (t & 31) * 8;  // fc1 h-octet of this thread
  float wf[8], bf_[8];
  {
    float4 w0 = *(const float4*)(W1 + c * HID + j8);
    float4 w1v = *(const float4*)(W1 + c * HID + j8 + 4);
    float4 bb0 = *(const float4*)(b1 + c * HID + j8);
    float4 bb1 = *(const float4*)(b1 + c * HID + j8 + 4);
    wf[0] = w0.x; wf[1] = w0.y; wf[2] = w0.z; wf[3] = w0.w;
    wf[4] = w1v.x; wf[5] = w1v.y; wf[6] = w1v.z; wf[7] = w1v.w;
    bf_[0] = bb0.x; bf_[1] = bb0.y; bf_[2] = bb0.z; bf_[3] = bb0.w;
    bf_[4] = bb1.x; bf_[5] = bb1.y; bf_[6] = bb1.z; bf_[7] = bb1.w;
  }
  // epilogue constants for this lane's n-columns: n = nw0 + jn*16 + l15  (r6 bug: nw0 was missing)
  float b2f[4], w3f[4][3];
#pragma unroll
  for (int jn = 0; jn < 4; ++jn) {
    int n = nw0 + jn * 16 + l15;
    b2f[jn] = b2[c * HID + n];
    w3f[jn][0] = W3[(c * HID + n) * 3 + 0];
    w3f[jn][1] = W3[(c * HID + n) * 3 + 1];
    w3f[jn][2] = W3[(c * HID + n) * 3 + 2];
  }
  const float b3f0 = b3[c * 3 + 0], b3f1 = b3[c * 3 + 1], b3f2 = b3[c * 3 + 2];
  const int bhalf = (lane >> 5) & 1;

  const floatx4 zero4 = {0.f, 0.f, 0.f, 0.f};

  // =================== tile loop: 8 x 64 pixels ===================
  for (int tile = 0; tile < 8; ++tile) {
    const int m0 = (g * 8 + tile) * 64;

    // ---- x rows for this wave: lanes 0..15 load, others receive via shfl
    float xr = 0.0f;
    if (lane < 16) {
      int ml = (lane >> 1) * 8 + wv * 2 + (lane & 1);
      xr = x[(size_t)(m0 + ml) * C_CH + c];
    }

    // ---- fc1: h1[m][h] = relu(x[m]*W1 + b1), fp32 -> bf16 LDS
#pragma unroll
    for (int it = 0; it < 8; ++it) {
      int m = it * 8 + (t >> 5);
      float xm = __shfl(xr, it * 2 + bhalf, 64);
      bf16x8 hv;
#pragma unroll
      for (int q = 0; q < 8; ++q)
        hv[q] = (bf16_t)fmaxf(xm * wf[q] + bf_[q], 0.0f);
      *(bf16x8*)&h1[m][j8] = hv;
    }
    __syncthreads();  // (A) h1 ready; also orders red-write(i) after red-read(i-1)

    // ---- fc2 K-loop: pure LDS + MFMA (B resident in registers)
    floatx4 acc[4][4];
#pragma unroll
    for (int im = 0; im < 4; ++im)
#pragma unroll
      for (int jn = 0; jn < 4; ++jn) acc[im][jn] = zero4;
#pragma unroll
    for (int kt = 0; kt < 4; ++kt) {
#pragma unroll
      for (int ks = 0; ks < 2; ++ks) {
        const int k0 = kt * 64 + ks * 32;
        bf16x8 af[4];
#pragma unroll
        for (int im = 0; im < 4; ++im)
          af[im] = *(const bf16x8*)&h1[im * 16 + l15][k0 + l4 * 8];
#pragma unroll
        for (int im = 0; im < 4; ++im)
#pragma unroll
          for (int jn = 0; jn < 4; ++jn)
            acc[im][jn] = __builtin_amdgcn_mfma_f32_16x16x32_bf16(
                af[im], Bf[kt * 8 + ks * 4 + jn], acc[im][jn], 0, 0, 0);
      }
    }

    // ---- fused epilogue: h2 = relu(acc+b2) fp32; fc3 dot; reduce over the 16
    // n-lanes (l15) via shfl_xor; lanes l15<3 hold the wave partial -> red LDS.
    // acc C/D layout (m89): col(n) = nw0 + jn*16 + l15, row(m) = im*16 + l4*4 + r
#pragma unroll
    for (int im = 0; im < 4; ++im) {
#pragma unroll
      for (int r = 0; r < 4; ++r) {
        float p0 = 0.f, p1 = 0.f, p2 = 0.f;
#pragma unroll
        for (int jn = 0; jn < 4; ++jn) {
          float h2v = fmaxf(acc[im][jn][r] + b2f[jn], 0.0f);
          p0 += h2v * w3f[jn][0];
          p1 += h2v * w3f[jn][1];
          p2 += h2v * w3f[jn][2];
        }
#pragma unroll
        for (int mask = 1; mask < 16; mask <<= 1) {
          p0 += __shfl_xor(p0, mask, 64);
          p1 += __shfl_xor(p1, mask, 64);
          p2 += __shfl_xor(p2, mask, 64);
        }
        if (l15 < 3) {
          int m = im * 16 + l4 * 4 + r;
          red[wv][m][l15] = (l15 == 0) ? p0 : (l15 == 1) ? p1 : p2;
        }
      }
    }
    __syncthreads();  // (C) red ready; also frees h1 for next tile's fc1

    // ---- cross-wave reduce + b3 + fp32 store: flat idx = (pixel*16+c)*3 + o
    if (t < 192) {
      int m = t / 3, o = t - m * 3;
      float s = red[0][m][o] + red[1][m][o] + red[2][m][o] + red[3][m][o];
      s += (o == 0) ? b3f0 : (o == 1) ? b3f1 : b3f2;
      out[(size_t)((m0 + m) * C_CH + c) * 3 + o] = s;
    }
    // next tile: fc1 h1-write is ordered after (C); red-write after next (A)
  }
}

extern "C" void kernel_launch(void* const* d_in, const int* in_sizes, int n_in,
                              void* d_out, int out_size, void* d_ws, size_t ws_size,
                              hipStream_t stream) {
  const float* x = (const float*)d_in[0];
  const float* W1 = (const float*)d_in[1];
  const float* b1 = (const float*)d_in[2];
  const float* W2 = (const float*)d_in[3];
  const float* b2 = (const float*)d_in[4];
  const float* W3 = (const float*)d_in[5];
  const float* b3 = (const float*)d_in[6];
  float* out = (float*)d_out;
  bf16_t* W2t = (bf16_t*)d_ws;  // 2 MB scratch: bf16-transposed W2

  const size_t need = (size_t)C_CH * HID * HID * sizeof(bf16_t);  // 2 MB
  // 16 channels x 64 groups; each block does 8 tiles of 64 pixels.
  if (ws_size >= need) {
    transpose_w2<<<256, 256, 0, stream>>>(W2, W2t);
    kan_fused<false><<<1024, 256, 0, stream>>>(x, W1, b1, W2t, W2, b2, W3, b3, out);
  } else {
    kan_fused<true><<<1024, 256, 0, stream>>>(x, W1, b1, W2t, W2, b2, W3, b3, out);
  }
}

// Round 8
// 162.775 us; speedup vs baseline: 1.5226x; 1.2447x over previous
//
#include <hip/hip_runtime.h>
#include <hip/hip_bf16.h>

// Per-channel 3-layer MLP (1 -> 256 -> 256 -> 3), N=B*H*W=32768 pixels, C=16.
// fp32 in / fp32 out; internal bf16 MFMA. fc2: 16 GEMMs M=32768,K=256,N=256.
//
// Round-8: persistent-B (r7) + MFMA fc3 (r4). r7's VALU+shfl fc3 epilogue was
// ~320 VALU + 192 bpermute per tile/wave vs 128 MFMA -> VALUBusy 31% > MfmaUtil
// 18.7%. MFMA fc3 costs ~60 VALU + 24 DS + 8 MFMA. Grid 512 x 16 tiles/block
// (exactly 2 blocks/CU resident, B loaded once per 16 tiles).

typedef __bf16 bf16_t;
typedef __attribute__((ext_vector_type(8))) __bf16 bf16x8;
typedef __attribute__((ext_vector_type(4))) float floatx4;

#define C_CH  16
#define HID   256
#define TILES 16

// ---------------------------------------------------------------------------
// Kernel 1: W2 fp32 [c][h][n] -> W2t bf16 [c][n][h]
// ---------------------------------------------------------------------------
__global__ __launch_bounds__(256) void transpose_w2(const float* __restrict__ W2,
                                                    bf16_t* __restrict__ W2t) {
  __shared__ __align__(16) bf16_t tl[64][72];  // +8 pad
  const int bid = blockIdx.x;
  const int c = bid >> 4, ti = (bid >> 2) & 3, tj = bid & 3;
  const int t = threadIdx.x;
  const float* src = W2 + (size_t)(c * 256 + tj * 64) * 256 + ti * 64;
#pragma unroll
  for (int it = 0; it < 4; ++it) {
    int idx = it * 256 + t;
    int h = idx >> 4, q = idx & 15;
    float4 v = *(const float4*)(src + h * 256 + q * 4);
    tl[h][q * 4 + 0] = (bf16_t)v.x;
    tl[h][q * 4 + 1] = (bf16_t)v.y;
    tl[h][q * 4 + 2] = (bf16_t)v.z;
    tl[h][q * 4 + 3] = (bf16_t)v.w;
  }
  __syncthreads();
  bf16_t* dst = W2t + (size_t)(c * 256 + ti * 64) * 256 + tj * 64;
#pragma unroll
  for (int it = 0; it < 2; ++it) {
    int idx = it * 256 + t;
    int n = idx >> 3, h8 = (idx & 7) * 8;
    bf16x8 tmp;
#pragma unroll
    for (int q = 0; q < 8; ++q) tmp[q] = tl[h8 + q][n];
    *(bf16x8*)(dst + n * 256 + h8) = tmp;
  }
}

// ---------------------------------------------------------------------------
// Kernel 2: persistent-B fused kernel. Block = 256 thr = 4 waves; one channel,
// 16 tiles of 64 pixels. Wave n-slice = 64; 4x4 mfma_f32_16x16x32_bf16 per tile.
// ---------------------------------------------------------------------------
template <bool DIRECT>
__global__ __launch_bounds__(256, 2) void kan_fused(
    const float* __restrict__ x, const float* __restrict__ W1,
    const float* __restrict__ b1, const bf16_t* __restrict__ W2t,
    const float* __restrict__ W2, const float* __restrict__ b2,
    const float* __restrict__ W3, const float* __restrict__ b3,
    float* __restrict__ out) {
  __shared__ __align__(16) bf16_t h1[64][264];  // 33792 B A-tile (h1, then h2)
  __shared__ __align__(16) bf16_t w3t[4][264];  //  2112 B W3^T B-operand (row3=0)
  __shared__ float red[4][64][3];               //  3072 B fc3 cross-wave partials

  const int t = threadIdx.x;
  const int lane = t & 63;
  const int wv = t >> 6;
  const int bid = blockIdx.x;
  const int c = bid & 15;   // channel (spread across consecutive blocks -> XCDs)
  const int g = bid >> 4;   // 16-tile group, 0..31

  const int l15 = lane & 15;
  const int l4 = lane >> 4;
  const int nw0 = wv * 64;  // wave's output-column base within HID

  // ---- persistent B: all 32 fragments for K=256 x n-slice 64 (128 VGPRs)
  bf16x8 Bf[32];  // [kt*8 + ks*4 + jn]
  if (!DIRECT) {
    const bf16_t* Bbase = W2t + ((size_t)c << 16) + (size_t)(nw0 + l15) * HID + l4 * 8;
#pragma unroll
    for (int kt = 0; kt < 4; ++kt)
#pragma unroll
      for (int ks = 0; ks < 2; ++ks)
#pragma unroll
        for (int jn = 0; jn < 4; ++jn)
          Bf[kt * 8 + ks * 4 + jn] =
              *(const bf16x8*)(Bbase + jn * (16 * HID) + kt * 64 + ks * 32);
  } else {
#pragma unroll
    for (int kt = 0; kt < 4; ++kt)
#pragma unroll
      for (int ks = 0; ks < 2; ++ks)
#pragma unroll
        for (int jn = 0; jn < 4; ++jn) {
          const float* gp = W2 + ((size_t)c << 16) +
                            (size_t)(kt * 64 + ks * 32 + l4 * 8) * HID +
                            (nw0 + jn * 16 + l15);
#pragma unroll
          for (int j = 0; j < 8; ++j) Bf[kt * 8 + ks * 4 + jn][j] = (bf16_t)gp[j * HID];
        }
  }

  // ---- per-block invariants
  const int j8 = (t & 31) * 8;  // fc1 h-octet of this thread
  float wf[8], bf_[8];
  {
    float4 w0 = *(const float4*)(W1 + c * HID + j8);
    float4 w1v = *(const float4*)(W1 + c * HID + j8 + 4);
    float4 bb0 = *(const float4*)(b1 + c * HID + j8);
    float4 bb1 = *(const float4*)(b1 + c * HID + j8 + 4);
    wf[0] = w0.x; wf[1] = w0.y; wf[2] = w0.z; wf[3] = w0.w;
    wf[4] = w1v.x; wf[5] = w1v.y; wf[6] = w1v.z; wf[7] = w1v.w;
    bf_[0] = bb0.x; bf_[1] = bb0.y; bf_[2] = bb0.z; bf_[3] = bb0.w;
    bf_[4] = bb1.x; bf_[5] = bb1.y; bf_[6] = bb1.z; bf_[7] = bb1.w;
  }
  // h2-writeback constants for this lane's n-columns: n = nw0 + jn*16 + l15
  float b2f[4];
#pragma unroll
  for (int jn = 0; jn < 4; ++jn) b2f[jn] = b2[c * HID + (nw0 + jn * 16 + l15)];
  const float b3f0 = b3[c * 3 + 0], b3f1 = b3[c * 3 + 1], b3f2 = b3[c * 3 + 2];
  const int bhalf = (lane >> 5) & 1;

  // ---- stage W3^T (per-block constant; visibility ordered by barrier A of tile 0)
  w3t[0][t] = (bf16_t)W3[(c * HID + t) * 3 + 0];
  w3t[1][t] = (bf16_t)W3[(c * HID + t) * 3 + 1];
  w3t[2][t] = (bf16_t)W3[(c * HID + t) * 3 + 2];
  w3t[3][t] = (bf16_t)0.0f;  // zero row (fc3 acc cols 3..15 ignored)

  const floatx4 zero4 = {0.f, 0.f, 0.f, 0.f};

  // =================== tile loop: 16 x 64 pixels ===================
  for (int tile = 0; tile < TILES; ++tile) {
    const int m0 = (g * TILES + tile) * 64;

    // ---- x rows for this wave: lanes 0..15 load, others receive via shfl
    float xr = 0.0f;
    if (lane < 16) {
      int ml = (lane >> 1) * 8 + wv * 2 + (lane & 1);
      xr = x[(size_t)(m0 + ml) * C_CH + c];
    }

    // ---- fc1: h1[m][h] = relu(x[m]*W1 + b1), fp32 -> bf16 LDS
#pragma unroll
    for (int it = 0; it < 8; ++it) {
      int m = it * 8 + (t >> 5);
      float xm = __shfl(xr, it * 2 + bhalf, 64);
      bf16x8 hv;
#pragma unroll
      for (int q = 0; q < 8; ++q)
        hv[q] = (bf16_t)fmaxf(xm * wf[q] + bf_[q], 0.0f);
      *(bf16x8*)&h1[m][j8] = hv;
    }
    __syncthreads();  // (A) h1 ready (also orders w3t staging & red-read of i-1)

    // ---- fc2 K-loop: pure LDS + MFMA (B resident in registers)
    floatx4 acc[4][4];
#pragma unroll
    for (int im = 0; im < 4; ++im)
#pragma unroll
      for (int jn = 0; jn < 4; ++jn) acc[im][jn] = zero4;
#pragma unroll
    for (int kt = 0; kt < 4; ++kt) {
#pragma unroll
      for (int ks = 0; ks < 2; ++ks) {
        const int k0 = kt * 64 + ks * 32;
        bf16x8 af[4];
#pragma unroll
        for (int im = 0; im < 4; ++im)
          af[im] = *(const bf16x8*)&h1[im * 16 + l15][k0 + l4 * 8];
#pragma unroll
        for (int im = 0; im < 4; ++im)
#pragma unroll
          for (int jn = 0; jn < 4; ++jn)
            acc[im][jn] = __builtin_amdgcn_mfma_f32_16x16x32_bf16(
                af[im], Bf[kt * 8 + ks * 4 + jn], acc[im][jn], 0, 0, 0);
      }
    }
    __syncthreads();  // (B) all waves done reading h1 before h2 overwrite

    // ---- h2 writeback: relu(acc + b2) -> h1 (bf16, A-layout for fc3)
    // acc C/D layout (m89): col(n) = nw0+jn*16+l15, row(m) = im*16 + l4*4 + r
#pragma unroll
    for (int im = 0; im < 4; ++im)
#pragma unroll
      for (int jn = 0; jn < 4; ++jn) {
        float bias = b2f[jn];
        int n = nw0 + jn * 16 + l15;
#pragma unroll
        for (int r = 0; r < 4; ++r)
          h1[im * 16 + l4 * 4 + r][n] = (bf16_t)fmaxf(acc[im][jn][r] + bias, 0.0f);
      }
    __syncthreads();  // (C) h2 complete

    // ---- fc3 via MFMA: out[m][o] = sum_h h2[m][h]*W3[c][h][o]; h split by wave
    {
      floatx4 acc3[4];
#pragma unroll
      for (int im = 0; im < 4; ++im) acc3[im] = zero4;
#pragma unroll
      for (int ks = 0; ks < 2; ++ks) {
        int kb = wv * 64 + ks * 32 + l4 * 8;
        int br = l15 < 3 ? l15 : 3;  // B row (o); row 3 = zeros
        bf16x8 bf3 = *(const bf16x8*)&w3t[br][kb];
#pragma unroll
        for (int im = 0; im < 4; ++im) {
          bf16x8 a3 = *(const bf16x8*)&h1[im * 16 + l15][kb];
          acc3[im] = __builtin_amdgcn_mfma_f32_16x16x32_bf16(a3, bf3, acc3[im], 0, 0, 0);
        }
      }
      if (l15 < 3) {
#pragma unroll
        for (int im = 0; im < 4; ++im)
#pragma unroll
          for (int r = 0; r < 4; ++r)
            red[wv][im * 16 + l4 * 4 + r][l15] = acc3[im][r];
      }
    }
    __syncthreads();  // (D) red ready; h1 free for next tile's fc1

    // ---- cross-wave reduce + b3 + fp32 store: flat idx = (pixel*16+c)*3 + o
    if (t < 192) {
      int m = t / 3, o = t - m * 3;
      float s = red[0][m][o] + red[1][m][o] + red[2][m][o] + red[3][m][o];
      s += (o == 0) ? b3f0 : (o == 1) ? b3f1 : b3f2;
      out[(size_t)((m0 + m) * C_CH + c) * 3 + o] = s;
    }
    // next tile's red-write is ordered after next (A); h1-write after (D) ✓
  }
}

extern "C" void kernel_launch(void* const* d_in, const int* in_sizes, int n_in,
                              void* d_out, int out_size, void* d_ws, size_t ws_size,
                              hipStream_t stream) {
  const float* x = (const float*)d_in[0];
  const float* W1 = (const float*)d_in[1];
  const float* b1 = (const float*)d_in[2];
  const float* W2 = (const float*)d_in[3];
  const float* b2 = (const float*)d_in[4];
  const float* W3 = (const float*)d_in[5];
  const float* b3 = (const float*)d_in[6];
  float* out = (float*)d_out;
  bf16_t* W2t = (bf16_t*)d_ws;  // 2 MB scratch: bf16-transposed W2

  const size_t need = (size_t)C_CH * HID * HID * sizeof(bf16_t);  // 2 MB
  // 16 channels x 32 groups = 512 blocks; each block: 16 tiles of 64 pixels.
  // 512 blocks / 256 CUs at 2 blocks/CU resident = one full dispatch round.
  if (ws_size >= need) {
    transpose_w2<<<256, 256, 0, stream>>>(W2, W2t);
    kan_fused<false><<<512, 256, 0, stream>>>(x, W1, b1, W2t, W2, b2, W3, b3, out);
  } else {
    kan_fused<true><<<512, 256, 0, stream>>>(x, W1, b1, W2t, W2, b2, W3, b3, out);
  }
}

// Round 9
// 144.870 us; speedup vs baseline: 1.7107x; 1.1236x over previous
//
#include <hip/hip_runtime.h>
#include <hip/hip_bf16.h>

// Per-channel 3-layer MLP (1 -> 256 -> 256 -> 3), N=B*H*W=32768 pixels, C=16.
// fp32 in / fp32 out; internal bf16 MFMA. fc2: 16 GEMMs M=32768,K=256,N=256.
//
// Round-9: r8 + (1) operand-swapped fc2 so h2 writeback packs to ds_write_b64,
// (2) quarter-m fc3 (wave owns 16 m-rows, full K) -> no red LDS / no reduce
// stage, direct global stores, (3) x(i+1) prefetch, (4) w3t stride 288.

typedef __bf16 bf16_t;
typedef __attribute__((ext_vector_type(8))) __bf16 bf16x8;
typedef __attribute__((ext_vector_type(4))) __bf16 bf16x4;
typedef __attribute__((ext_vector_type(4))) float floatx4;

#define C_CH  16
#define HID   256
#define TILES 16

// ---------------------------------------------------------------------------
// Kernel 1: W2 fp32 [c][h][n] -> W2t bf16 [c][n][h]
// ---------------------------------------------------------------------------
__global__ __launch_bounds__(256) void transpose_w2(const float* __restrict__ W2,
                                                    bf16_t* __restrict__ W2t) {
  __shared__ __align__(16) bf16_t tl[64][72];  // +8 pad
  const int bid = blockIdx.x;
  const int c = bid >> 4, ti = (bid >> 2) & 3, tj = bid & 3;
  const int t = threadIdx.x;
  const float* src = W2 + (size_t)(c * 256 + tj * 64) * 256 + ti * 64;
#pragma unroll
  for (int it = 0; it < 4; ++it) {
    int idx = it * 256 + t;
    int h = idx >> 4, q = idx & 15;
    float4 v = *(const float4*)(src + h * 256 + q * 4);
    tl[h][q * 4 + 0] = (bf16_t)v.x;
    tl[h][q * 4 + 1] = (bf16_t)v.y;
    tl[h][q * 4 + 2] = (bf16_t)v.z;
    tl[h][q * 4 + 3] = (bf16_t)v.w;
  }
  __syncthreads();
  bf16_t* dst = W2t + (size_t)(c * 256 + ti * 64) * 256 + tj * 64;
#pragma unroll
  for (int it = 0; it < 2; ++it) {
    int idx = it * 256 + t;
    int n = idx >> 3, h8 = (idx & 7) * 8;
    bf16x8 tmp;
#pragma unroll
    for (int q = 0; q < 8; ++q) tmp[q] = tl[h8 + q][n];
    *(bf16x8*)(dst + n * 256 + h8) = tmp;
  }
}

// ---------------------------------------------------------------------------
// Kernel 2: persistent-B fused kernel. Block = 256 thr = 4 waves; one channel,
// 16 tiles of 64 pixels. Wave n-slice = 64; 4x4 mfma_f32_16x16x32_bf16 per tile.
// ---------------------------------------------------------------------------
template <bool DIRECT>
__global__ __launch_bounds__(256, 2) void kan_fused(
    const float* __restrict__ x, const float* __restrict__ W1,
    const float* __restrict__ b1, const bf16_t* __restrict__ W2t,
    const float* __restrict__ W2, const float* __restrict__ b2,
    const float* __restrict__ W3, const float* __restrict__ b3,
    float* __restrict__ out) {
  __shared__ __align__(16) bf16_t h1[64][264];  // 33792 B A-tile (h1, then h2)
  __shared__ __align__(16) bf16_t w3t[4][288];  //  2304 B W3^T B-operand (row3=0)

  const int t = threadIdx.x;
  const int lane = t & 63;
  const int wv = t >> 6;
  const int bid = blockIdx.x;
  const int c = bid & 15;   // channel (consecutive blocks -> different channels/XCDs)
  const int g = bid >> 4;   // 16-tile group, 0..31

  const int l15 = lane & 15;
  const int l4 = lane >> 4;
  const int nw0 = wv * 64;  // wave's output-column base within HID

  // ---- persistent B: all 32 fragments for K=256 x n-slice 64 (128 VGPRs)
  // Bf lane layout: [n = nw0+jn*16+l15][k = kt*64+ks*32+l4*8 + j]
  bf16x8 Bf[32];  // [kt*8 + ks*4 + jn]
  if (!DIRECT) {
    const bf16_t* Bbase = W2t + ((size_t)c << 16) + (size_t)(nw0 + l15) * HID + l4 * 8;
#pragma unroll
    for (int kt = 0; kt < 4; ++kt)
#pragma unroll
      for (int ks = 0; ks < 2; ++ks)
#pragma unroll
        for (int jn = 0; jn < 4; ++jn)
          Bf[kt * 8 + ks * 4 + jn] =
              *(const bf16x8*)(Bbase + jn * (16 * HID) + kt * 64 + ks * 32);
  } else {
#pragma unroll
    for (int kt = 0; kt < 4; ++kt)
#pragma unroll
      for (int ks = 0; ks < 2; ++ks)
#pragma unroll
        for (int jn = 0; jn < 4; ++jn) {
          const float* gp = W2 + ((size_t)c << 16) +
                            (size_t)(kt * 64 + ks * 32 + l4 * 8) * HID +
                            (nw0 + jn * 16 + l15);
#pragma unroll
          for (int j = 0; j < 8; ++j) Bf[kt * 8 + ks * 4 + jn][j] = (bf16_t)gp[j * HID];
        }
  }

  // ---- per-block invariants
  const int j8 = (t & 31) * 8;  // fc1 h-octet of this thread
  float wf[8], bf_[8];
  {
    float4 w0 = *(const float4*)(W1 + c * HID + j8);
    float4 w1v = *(const float4*)(W1 + c * HID + j8 + 4);
    float4 bb0 = *(const float4*)(b1 + c * HID + j8);
    float4 bb1 = *(const float4*)(b1 + c * HID + j8 + 4);
    wf[0] = w0.x; wf[1] = w0.y; wf[2] = w0.z; wf[3] = w0.w;
    wf[4] = w1v.x; wf[5] = w1v.y; wf[6] = w1v.z; wf[7] = w1v.w;
    bf_[0] = bb0.x; bf_[1] = bb0.y; bf_[2] = bb0.z; bf_[3] = bb0.w;
    bf_[4] = bb1.x; bf_[5] = bb1.y; bf_[6] = bb1.z; bf_[7] = bb1.w;
  }
  // h2-writeback bias: lane's n-quads n = nw0 + jn*16 + l4*4 + r (swapped layout)
  floatx4 b2v[4];
#pragma unroll
  for (int jn = 0; jn < 4; ++jn)
    b2v[jn] = *(const floatx4*)(b2 + c * HID + nw0 + jn * 16 + l4 * 4);
  const float b3v = b3[c * 3 + (l15 < 3 ? l15 : 0)];
  const int bhalf = (lane >> 5) & 1;

  // ---- stage W3^T (per-block constant; first read is >=2 barriers later)
  w3t[0][t] = (bf16_t)W3[(c * HID + t) * 3 + 0];
  w3t[1][t] = (bf16_t)W3[(c * HID + t) * 3 + 1];
  w3t[2][t] = (bf16_t)W3[(c * HID + t) * 3 + 2];
  w3t[3][t] = (bf16_t)0.0f;  // zero row (fc3 acc cols 3..15 ignored)

  const floatx4 zero4 = {0.f, 0.f, 0.f, 0.f};

  // ---- x prefetch for tile 0
  float xr = 0.0f;
  {
    int ml = (lane >> 1) * 8 + wv * 2 + (lane & 1);
    if (lane < 16) xr = x[(size_t)(g * TILES * 64 + ml) * C_CH + c];
  }

  // =================== tile loop: 16 x 64 pixels ===================
  for (int tile = 0; tile < TILES; ++tile) {
    const int m0 = (g * TILES + tile) * 64;

    // ---- fc1: h1[m][h] = relu(x[m]*W1 + b1), fp32 -> bf16 LDS
#pragma unroll
    for (int it = 0; it < 8; ++it) {
      int m = it * 8 + (t >> 5);
      float xm = __shfl(xr, it * 2 + bhalf, 64);
      bf16x8 hv;
#pragma unroll
      for (int q = 0; q < 8; ++q)
        hv[q] = (bf16_t)fmaxf(xm * wf[q] + bf_[q], 0.0f);
      *(bf16x8*)&h1[m][j8] = hv;
    }
    __syncthreads();  // (A) h1 ready

    // ---- prefetch x for tile+1 (latency hidden behind fc2)
    float xr_n = 0.0f;
    if (tile + 1 < TILES && lane < 16) {
      int ml = (lane >> 1) * 8 + wv * 2 + (lane & 1);
      xr_n = x[(size_t)(m0 + 64 + ml) * C_CH + c];
    }

    // ---- fc2 K-loop: pure LDS + MFMA, OPERAND-SWAPPED: mfma(Bf, af)
    // D layout: col = l15 -> m = im*16+l15 ; row = l4*4+r -> n = nw0+jn*16+l4*4+r
    floatx4 acc[4][4];
#pragma unroll
    for (int im = 0; im < 4; ++im)
#pragma unroll
      for (int jn = 0; jn < 4; ++jn) acc[im][jn] = zero4;
#pragma unroll
    for (int kt = 0; kt < 4; ++kt) {
#pragma unroll
      for (int ks = 0; ks < 2; ++ks) {
        const int k0 = kt * 64 + ks * 32;
        bf16x8 af[4];
#pragma unroll
        for (int im = 0; im < 4; ++im)
          af[im] = *(const bf16x8*)&h1[im * 16 + l15][k0 + l4 * 8];
#pragma unroll
        for (int im = 0; im < 4; ++im)
#pragma unroll
          for (int jn = 0; jn < 4; ++jn)
            acc[im][jn] = __builtin_amdgcn_mfma_f32_16x16x32_bf16(
                Bf[kt * 8 + ks * 4 + jn], af[im], acc[im][jn], 0, 0, 0);
      }
    }
    __syncthreads();  // (B) all waves done reading h1 before h2 overwrite

    // ---- h2 writeback: relu(acc + b2) -> h1 (bf16), packed ds_write_b64
    // lane (im,jn): m = im*16+l15, n = nw0+jn*16+l4*4 .. +3  (consecutive!)
#pragma unroll
    for (int im = 0; im < 4; ++im)
#pragma unroll
      for (int jn = 0; jn < 4; ++jn) {
        bf16x4 hv;
#pragma unroll
        for (int r = 0; r < 4; ++r)
          hv[r] = (bf16_t)fmaxf(acc[im][jn][r] + b2v[jn][r], 0.0f);
        *(bf16x4*)&h1[im * 16 + l15][nw0 + jn * 16 + l4 * 4] = hv;
      }
    __syncthreads();  // (C) h2 complete

    // ---- fc3, quarter-m: wave wv owns m-rows [wv*16, wv*16+16), full K=256
    // A = h2[wv*16+l15][k], B = w3t[o][k]; D: col=o=l15, row=m_local=l4*4+r
    {
      floatx4 acc3 = zero4;
      const int br = l15 < 3 ? l15 : 3;  // row 3 = zeros
#pragma unroll
      for (int kk = 0; kk < 8; ++kk) {
        bf16x8 a3 = *(const bf16x8*)&h1[wv * 16 + l15][kk * 32 + l4 * 8];
        bf16x8 bf3 = *(const bf16x8*)&w3t[br][kk * 32 + l4 * 8];
        acc3 = __builtin_amdgcn_mfma_f32_16x16x32_bf16(a3, bf3, acc3, 0, 0, 0);
      }
      if (l15 < 3) {
        float* op = out + ((size_t)((m0 + wv * 16 + l4 * 4) * C_CH + c) * 3) + l15;
#pragma unroll
        for (int r = 0; r < 4; ++r) op[r * (C_CH * 3)] = acc3[r] + b3v;
      }
    }
    __syncthreads();  // (D) fc3 reads done; h1 free for next tile's fc1

    xr = xr_n;
  }
}

extern "C" void kernel_launch(void* const* d_in, const int* in_sizes, int n_in,
                              void* d_out, int out_size, void* d_ws, size_t ws_size,
                              hipStream_t stream) {
  const float* x = (const float*)d_in[0];
  const float* W1 = (const float*)d_in[1];
  const float* b1 = (const float*)d_in[2];
  const float* W2 = (const float*)d_in[3];
  const float* b2 = (const float*)d_in[4];
  const float* W3 = (const float*)d_in[5];
  const float* b3 = (const float*)d_in[6];
  float* out = (float*)d_out;
  bf16_t* W2t = (bf16_t*)d_ws;  // 2 MB scratch: bf16-transposed W2

  const size_t need = (size_t)C_CH * HID * HID * sizeof(bf16_t);  // 2 MB
  // 16 channels x 32 groups = 512 blocks; each block: 16 tiles of 64 pixels.
  // 2 blocks/CU resident -> exactly one dispatch round on 256 CUs.
  if (ws_size >= need) {
    transpose_w2<<<256, 256, 0, stream>>>(W2, W2t);
    kan_fused<false><<<512, 256, 0, stream>>>(x, W1, b1, W2t, W2, b2, W3, b3, out);
  } else {
    kan_fused<true><<<512, 256, 0, stream>>>(x, W1, b1, W2t, W2, b2, W3, b3, out);
  }
}